// Round 4
// baseline (77.863 us; speedup 1.0000x reference)
//
#include <hip/hip_runtime.h>
#include <hip/hip_bf16.h>

#define KCOLS 262144
#define LAT 64
#define HID 40

// ---------------------------------------------------------------------------
// Kernel 1: transpose the six weight matrices into d_ws (row-major by input
// index) so the main kernel's unrolled loops read consecutive uniform
// addresses (scalar cache). Layout (floats):
//   [0,2560)      W1oT[r*40+j] = W_o1[j*64+r]
//   [2560,5120)   W1tT[r*40+j] = W_t1[j*64+r]
//   [5120,6720)   W2oT[r*40+j] = W_o2[j*40+r]
//   [6720,8320)   W2tT[r*40+j] = W_t2[j*40+r]
//   [8320,8680)   W3oT[r*9+j]  = W_o3[j*40+r]
//   [8680,8800)   W3tT[r*3+j]  = W_t3[j*40+r]
// ---------------------------------------------------------------------------
__global__ __launch_bounds__(256) void transpose_w(
    const float* __restrict__ Wo1, const float* __restrict__ Wt1,
    const float* __restrict__ Wo2, const float* __restrict__ Wt2,
    const float* __restrict__ Wo3, const float* __restrict__ Wt3,
    float* __restrict__ ws)
{
    int t = blockIdx.x * blockDim.x + threadIdx.x;
    if (t < 2560) {
        int r = t / 40, j = t % 40;
        ws[t]        = Wo1[j * 64 + r];
        ws[2560 + t] = Wt1[j * 64 + r];
    }
    if (t < 1600) {
        int r = t / 40, j = t % 40;
        ws[5120 + t] = Wo2[j * 40 + r];
        ws[6720 + t] = Wt2[j * 40 + r];
    }
    if (t < 360) {
        int r = t / 9, j = t % 9;
        ws[8320 + t] = Wo3[j * 40 + r];
    }
    if (t < 120) {
        int r = t / 3, j = t % 3;
        ws[8680 + t] = Wt3[j * 40 + r];
    }
}

// ---------------------------------------------------------------------------
// Kernel 2: branch-split fused kernel; layer-1 x loads batched 8-deep so each
// wave keeps 8 global loads in flight during the 320-FMA chunk (hides ~900cy
// HBM latency). blockIdx.y==0 -> omega+expm (rows 0..17); ==1 -> translation
// (rows 18..20).
// ---------------------------------------------------------------------------
__global__ __launch_bounds__(256) void fused_split(
    const float* __restrict__ x,
    const float* __restrict__ ws,
    const float* __restrict__ bo1, const float* __restrict__ bo2,
    const float* __restrict__ bo3, const float* __restrict__ bt1,
    const float* __restrict__ bt2, const float* __restrict__ bt3,
    float* __restrict__ out)
{
    const int k = blockIdx.x * blockDim.x + threadIdx.x;  // column index

    if (blockIdx.y == 0) {
        // ================= OMEGA branch =================
        const float* W1 = ws;            // 64x40
        const float* W2 = ws + 5120;     // 40x40
        const float* W3 = ws + 8320;     // 40x9

        float h[HID];
#pragma unroll
        for (int j = 0; j < HID; ++j) h[j] = bo1[j];

        for (int r0 = 0; r0 < LAT; r0 += 8) {
            float xv[8];
#pragma unroll
            for (int u = 0; u < 8; ++u)
                xv[u] = x[(size_t)(r0 + u) * KCOLS + k];
#pragma unroll
            for (int u = 0; u < 8; ++u) {
                const float* w = W1 + (r0 + u) * HID;
#pragma unroll
                for (int j = 0; j < HID; ++j) h[j] = fmaf(w[j], xv[u], h[j]);
            }
        }
#pragma unroll
        for (int j = 0; j < HID; ++j) h[j] = fmaxf(h[j], 0.0f);

        float g[HID];
#pragma unroll
        for (int j = 0; j < HID; ++j) g[j] = bo2[j];
        for (int r = 0; r < HID; ++r) {
            float hv = h[r];
            const float* w = W2 + r * HID;
#pragma unroll
            for (int j = 0; j < HID; ++j) g[j] = fmaf(w[j], hv, g[j]);
        }

        float om[9];
#pragma unroll
        for (int j = 0; j < 9; ++j) om[j] = bo3[j];
        for (int r = 0; r < HID; ++r) {
            float hv = fmaxf(g[r], 0.0f);
            const float* w = W3 + r * 9;
#pragma unroll
            for (int j = 0; j < 9; ++j) om[j] = fmaf(w[j], hv, om[j]);
        }
#pragma unroll
        for (int j = 0; j < 9; ++j) om[j] = fmaxf(om[j], 0.0f);

#pragma unroll
        for (int j = 0; j < 9; ++j)
            out[(size_t)j * KCOLS + k] = om[j];

        // expm: scale 1/32, Taylor-9 Horner, 5 squarings
        float B[9];
#pragma unroll
        for (int i = 0; i < 9; ++i) B[i] = om[i] * (1.0f / 32.0f);

        float T[9] = {1.f, 0.f, 0.f, 0.f, 1.f, 0.f, 0.f, 0.f, 1.f};
#pragma unroll
        for (int m = 9; m >= 1; --m) {
            float U[9];
#pragma unroll
            for (int rr = 0; rr < 3; ++rr)
#pragma unroll
                for (int cc = 0; cc < 3; ++cc)
                    U[rr * 3 + cc] = B[rr * 3 + 0] * T[0 * 3 + cc]
                                   + B[rr * 3 + 1] * T[1 * 3 + cc]
                                   + B[rr * 3 + 2] * T[2 * 3 + cc];
            const float s = 1.0f / (float)m;
#pragma unroll
            for (int i = 0; i < 9; ++i)
                T[i] = U[i] * s + ((i == 0 || i == 4 || i == 8) ? 1.0f : 0.0f);
        }
#pragma unroll
        for (int q = 0; q < 5; ++q) {
            float U[9];
#pragma unroll
            for (int rr = 0; rr < 3; ++rr)
#pragma unroll
                for (int cc = 0; cc < 3; ++cc)
                    U[rr * 3 + cc] = T[rr * 3 + 0] * T[0 * 3 + cc]
                                   + T[rr * 3 + 1] * T[1 * 3 + cc]
                                   + T[rr * 3 + 2] * T[2 * 3 + cc];
#pragma unroll
            for (int i = 0; i < 9; ++i) T[i] = U[i];
        }
#pragma unroll
        for (int j = 0; j < 9; ++j)
            out[(size_t)(9 + j) * KCOLS + k] = T[j];
    } else {
        // ================= TRANSLATION branch =================
        const float* W1 = ws + 2560;     // 64x40
        const float* W2 = ws + 6720;     // 40x40
        const float* W3 = ws + 8680;     // 40x3

        float h[HID];
#pragma unroll
        for (int j = 0; j < HID; ++j) h[j] = bt1[j];

        for (int r0 = 0; r0 < LAT; r0 += 8) {
            float xv[8];
#pragma unroll
            for (int u = 0; u < 8; ++u)
                xv[u] = x[(size_t)(r0 + u) * KCOLS + k];
#pragma unroll
            for (int u = 0; u < 8; ++u) {
                const float* w = W1 + (r0 + u) * HID;
#pragma unroll
                for (int j = 0; j < HID; ++j) h[j] = fmaf(w[j], xv[u], h[j]);
            }
        }
#pragma unroll
        for (int j = 0; j < HID; ++j) h[j] = fmaxf(h[j], 0.0f);

        float g[HID];
#pragma unroll
        for (int j = 0; j < HID; ++j) g[j] = bt2[j];
        for (int r = 0; r < HID; ++r) {
            float hv = h[r];
            const float* w = W2 + r * HID;
#pragma unroll
            for (int j = 0; j < HID; ++j) g[j] = fmaf(w[j], hv, g[j]);
        }

        float tr[3];
#pragma unroll
        for (int j = 0; j < 3; ++j) tr[j] = bt3[j];
        for (int r = 0; r < HID; ++r) {
            float hv = fmaxf(g[r], 0.0f);
            const float* w = W3 + r * 3;
#pragma unroll
            for (int j = 0; j < 3; ++j) tr[j] = fmaf(w[j], hv, tr[j]);
        }
#pragma unroll
        for (int j = 0; j < 3; ++j)
            out[(size_t)(18 + j) * KCOLS + k] = fmaxf(tr[j], 0.0f);
    }
}

extern "C" void kernel_launch(void* const* d_in, const int* in_sizes, int n_in,
                              void* d_out, int out_size, void* d_ws, size_t ws_size,
                              hipStream_t stream) {
    const float* x   = (const float*)d_in[0];
    const float* Wo1 = (const float*)d_in[1];
    const float* bo1 = (const float*)d_in[2];
    const float* Wo2 = (const float*)d_in[3];
    const float* bo2 = (const float*)d_in[4];
    const float* Wo3 = (const float*)d_in[5];
    const float* bo3 = (const float*)d_in[6];
    const float* Wt1 = (const float*)d_in[7];
    const float* bt1 = (const float*)d_in[8];
    const float* Wt2 = (const float*)d_in[9];
    const float* bt2 = (const float*)d_in[10];
    const float* Wt3 = (const float*)d_in[11];
    const float* bt3 = (const float*)d_in[12];

    float* ws = (float*)d_ws;
    float* out = (float*)d_out;

    hipLaunchKernelGGL(transpose_w, dim3(10), dim3(256), 0, stream,
                       Wo1, Wt1, Wo2, Wt2, Wo3, Wt3, ws);
    hipLaunchKernelGGL(fused_split, dim3(KCOLS / 256, 2), dim3(256), 0, stream,
                       x, ws, bo1, bo2, bo3, bt1, bt2, bt3, out);
}

// Round 5
// 40.829 us; speedup vs baseline: 1.9070x; 1.9070x over previous
//
#include <hip/hip_runtime.h>
#include <hip/hip_bf16.h>

#define KC 262144

typedef __attribute__((ext_vector_type(8))) short bf16x8;
typedef __attribute__((ext_vector_type(4))) float f32x4;
typedef unsigned short u16;
typedef unsigned int u32;

__device__ __forceinline__ u16 f2bf(float f) {
    u32 u = __float_as_uint(f);
    return (u16)((u + 0x7fffu + ((u >> 16) & 1u)) >> 16);   // RNE, finite vals
}
__device__ __forceinline__ u32 pk2(float a, float b) {
    return (u32)f2bf(a) | ((u32)f2bf(b) << 16);
}
__device__ __forceinline__ float bf2f(u32 h) {
    return __uint_as_float(h << 16);
}

// ---------------------------------------------------------------------------
// Prep: build stacked bf16 weight matrices in ws (bias absorbed at k==80 via
// ones-row trick for L2/L3; L1 bias kept f32 for accumulator init).
//   W1s u16[80][64]   rows 0..39 = W_o1, 40..79 = W_t1
//   W2s u16[80][96]   block-diag W_o2/W_t2, col 80 = bias, rest 0
//   W3s u16[16][96]   rows 0..8 = W_o3 | 9..11 = W_t3 (cols 40..79) | 12..15 = 0
//   b1s f32[80]       [b_o1 ; b_t1]
// ---------------------------------------------------------------------------
__global__ __launch_bounds__(256) void prep(
    const float* __restrict__ Wo1, const float* __restrict__ bo1,
    const float* __restrict__ Wo2, const float* __restrict__ bo2,
    const float* __restrict__ Wo3, const float* __restrict__ bo3,
    const float* __restrict__ Wt1, const float* __restrict__ bt1,
    const float* __restrict__ Wt2, const float* __restrict__ bt2,
    const float* __restrict__ Wt3, const float* __restrict__ bt3,
    u16* __restrict__ ws)
{
    u16* W1s = ws;                      // 5120 u16
    u16* W2s = ws + 5120;               // 7680 u16
    u16* W3s = ws + 12800;              // 1536 u16
    float* b1s = (float*)(ws + 14336);  // 80 f32
    const int t0 = blockIdx.x * 256 + threadIdx.x;
    const int NT = gridDim.x * 256;

    for (int i = t0; i < 5120; i += NT) {
        int r = i >> 6, k = i & 63;
        float v = (r < 40) ? Wo1[r * 64 + k] : Wt1[(r - 40) * 64 + k];
        W1s[i] = f2bf(v);
    }
    for (int i = t0; i < 7680; i += NT) {
        int r = i / 96, k = i - r * 96;
        float v = 0.f;
        if (r < 40) {
            if (k < 40) v = Wo2[r * 40 + k];
            else if (k == 80) v = bo2[r];
        } else {
            int rr = r - 40;
            if (k >= 40 && k < 80) v = Wt2[rr * 40 + (k - 40)];
            else if (k == 80) v = bt2[rr];
        }
        W2s[i] = f2bf(v);
    }
    for (int i = t0; i < 1536; i += NT) {
        int r = i / 96, k = i - r * 96;
        float v = 0.f;
        if (r < 9) {
            if (k < 40) v = Wo3[r * 40 + k];
            else if (k == 80) v = bo3[r];
        } else if (r < 12) {
            int rr = r - 9;
            if (k >= 40 && k < 80) v = Wt3[rr * 40 + (k - 40)];
            else if (k == 80) v = bt3[rr];
        }
        W3s[i] = f2bf(v);
    }
    for (int i = t0; i < 80; i += NT)
        b1s[i] = (i < 40) ? bo1[i] : bt1[i - 40];
}

// ---------------------------------------------------------------------------
// Main: per wave, 2 iters x 64 columns. Per 16-col tile:
//   L1 (5 M-tiles x 2 K) -> relu -> LDS col-major bf16 -> L2 (5x3, bias via
//   ones-row) -> relu -> same LDS -> L3 (1x3) -> relu -> l3s staging.
// Then per-column phase: lane<->column, expm on VALU, f32 stores.
// LDS is per-wave private (no barriers).
// ---------------------------------------------------------------------------
__global__ __launch_bounds__(256, 2) void mlp_mfma(
    const float* __restrict__ x, const u16* __restrict__ ws,
    float* __restrict__ out)
{
    const u16* W1s = ws;
    const u16* W2s = ws + 5120;
    const u16* W3s = ws + 12800;
    const float* b1s = (const float*)(ws + 14336);

    __shared__ u16 hst[4][16][104];   // [wave][col][row(96 used, pad 104)]
    __shared__ u16 l3s[4][64][16];    // [wave][col-in-iter][row]

    const int tid = threadIdx.x;
    const int wid = tid >> 6;
    const int lane = tid & 63;
    const int g = lane >> 4;
    const int c = lane & 15;
    const int wgid = blockIdx.x * 4 + wid;   // 0..2047

    // ---- persistent A-fragments (weights) ----
    bf16x8 A1[5][2], A2[5][3], A3[3];
    f32x4 b1v[5];
#pragma unroll
    for (int m = 0; m < 5; ++m) {
#pragma unroll
        for (int s = 0; s < 2; ++s)
            A1[m][s] = *(const bf16x8*)(W1s + (16 * m + c) * 64 + 32 * s + 8 * g);
#pragma unroll
        for (int s = 0; s < 3; ++s)
            A2[m][s] = *(const bf16x8*)(W2s + (16 * m + c) * 96 + 32 * s + 8 * g);
        b1v[m] = *(const f32x4*)(b1s + 16 * m + 4 * g);
    }
#pragma unroll
    for (int s = 0; s < 3; ++s)
        A3[s] = *(const bf16x8*)(W3s + c * 96 + 32 * s + 8 * g);

    // ---- hstage pad rows 80..95: row 80 = 1.0 (bias row), 81..95 = 0 ----
    {
        uint2 z;
        z.x = (g == 0) ? 0x00003f80u : 0u;
        z.y = 0u;
        *(uint2*)&hst[wid][c][80 + 4 * g] = z;
    }

    // ---- per-lane x byte-offset table (B-frag pattern) ----
    u32 xoff[16];
#pragma unroll
    for (int jj = 0; jj < 16; ++jj) {
        int row = 8 * g + (jj & 7) + 32 * (jj >> 3);
        xoff[jj] = (u32)((row * KC + wgid * 128 + c) * 4);
    }
    const char* xb_ = (const char*)x;

    for (int it = 0; it < 2; ++it) {
        const int cbase = wgid * 128 + it * 64;
        const u32 itoff = (u32)(it * 256);

#pragma unroll
        for (int t = 0; t < 4; ++t) {
            // x tile loads (already in B-frag lane pattern)
            float xr[16];
#pragma unroll
            for (int jj = 0; jj < 16; ++jj)
                xr[jj] = *(const float*)(xb_ + (xoff[jj] + itoff + t * 64));
            bf16x8 xv[2];
#pragma unroll
            for (int s = 0; s < 2; ++s) {
                union { u32 u[4]; bf16x8 v; } uu;
#pragma unroll
                for (int p = 0; p < 4; ++p)
                    uu.u[p] = pk2(xr[8 * s + 2 * p], xr[8 * s + 2 * p + 1]);
                xv[s] = uu.v;
            }

            // ---- L1 ----
            f32x4 a1[5];
#pragma unroll
            for (int m = 0; m < 5; ++m) a1[m] = b1v[m];
#pragma unroll
            for (int s = 0; s < 2; ++s)
#pragma unroll
                for (int m = 0; m < 5; ++m)
                    a1[m] = __builtin_amdgcn_mfma_f32_16x16x32_bf16(
                        A1[m][s], xv[s], a1[m], 0, 0, 0);
#pragma unroll
            for (int m = 0; m < 5; ++m) {
                uint2 w;
                w.x = pk2(fmaxf(a1[m][0], 0.f), fmaxf(a1[m][1], 0.f));
                w.y = pk2(fmaxf(a1[m][2], 0.f), fmaxf(a1[m][3], 0.f));
                *(uint2*)&hst[wid][c][16 * m + 4 * g] = w;
            }

            // ---- L2 (K=96: h1 rows + ones-row + zeros) ----
            f32x4 a2[5];
#pragma unroll
            for (int m = 0; m < 5; ++m) a2[m] = f32x4{0.f, 0.f, 0.f, 0.f};
#pragma unroll
            for (int s = 0; s < 3; ++s) {
                bf16x8 hb = *(const bf16x8*)&hst[wid][c][32 * s + 8 * g];
#pragma unroll
                for (int m = 0; m < 5; ++m)
                    a2[m] = __builtin_amdgcn_mfma_f32_16x16x32_bf16(
                        A2[m][s], hb, a2[m], 0, 0, 0);
            }
#pragma unroll
            for (int m = 0; m < 5; ++m) {
                uint2 w;
                w.x = pk2(fmaxf(a2[m][0], 0.f), fmaxf(a2[m][1], 0.f));
                w.y = pk2(fmaxf(a2[m][2], 0.f), fmaxf(a2[m][3], 0.f));
                *(uint2*)&hst[wid][c][16 * m + 4 * g] = w;
            }

            // ---- L3 ----
            f32x4 a3 = f32x4{0.f, 0.f, 0.f, 0.f};
#pragma unroll
            for (int s = 0; s < 3; ++s) {
                bf16x8 hb = *(const bf16x8*)&hst[wid][c][32 * s + 8 * g];
                a3 = __builtin_amdgcn_mfma_f32_16x16x32_bf16(
                    A3[s], hb, a3, 0, 0, 0);
            }
            {
                uint2 w;
                w.x = pk2(fmaxf(a3[0], 0.f), fmaxf(a3[1], 0.f));
                w.y = pk2(fmaxf(a3[2], 0.f), fmaxf(a3[3], 0.f));
                *(uint2*)&l3s[wid][16 * t + c][4 * g] = w;
            }
        }

        // ---- per-column phase: lane <-> column cbase+lane ----
        {
            uint4 q0 = *(const uint4*)&l3s[wid][lane][0];
            uint4 q1 = *(const uint4*)&l3s[wid][lane][8];
            float om[9];
            om[0] = bf2f(q0.x & 0xffffu); om[1] = bf2f(q0.x >> 16);
            om[2] = bf2f(q0.y & 0xffffu); om[3] = bf2f(q0.y >> 16);
            om[4] = bf2f(q0.z & 0xffffu); om[5] = bf2f(q0.z >> 16);
            om[6] = bf2f(q0.w & 0xffffu); om[7] = bf2f(q0.w >> 16);
            om[8] = bf2f(q1.x & 0xffffu);
            float tr0 = bf2f(q1.x >> 16);
            float tr1 = bf2f(q1.y & 0xffffu);
            float tr2 = bf2f(q1.y >> 16);

            const size_t ob = (size_t)cbase + lane;
#pragma unroll
            for (int j = 0; j < 9; ++j)
                out[(size_t)j * KC + ob] = om[j];
            out[(size_t)18 * KC + ob] = tr0;
            out[(size_t)19 * KC + ob] = tr1;
            out[(size_t)20 * KC + ob] = tr2;

            // expm: scale 1/32, Taylor-9 Horner, 5 squarings
            float B[9];
#pragma unroll
            for (int i = 0; i < 9; ++i) B[i] = om[i] * (1.0f / 32.0f);
            float T[9] = {1.f, 0.f, 0.f, 0.f, 1.f, 0.f, 0.f, 0.f, 1.f};
#pragma unroll
            for (int m = 9; m >= 1; --m) {
                float U[9];
#pragma unroll
                for (int rr = 0; rr < 3; ++rr)
#pragma unroll
                    for (int cc = 0; cc < 3; ++cc)
                        U[rr * 3 + cc] = B[rr * 3 + 0] * T[0 * 3 + cc]
                                       + B[rr * 3 + 1] * T[1 * 3 + cc]
                                       + B[rr * 3 + 2] * T[2 * 3 + cc];
                const float s = 1.0f / (float)m;
#pragma unroll
                for (int i = 0; i < 9; ++i)
                    T[i] = U[i] * s + ((i == 0 || i == 4 || i == 8) ? 1.0f : 0.0f);
            }
#pragma unroll
            for (int q = 0; q < 5; ++q) {
                float U[9];
#pragma unroll
                for (int rr = 0; rr < 3; ++rr)
#pragma unroll
                    for (int cc = 0; cc < 3; ++cc)
                        U[rr * 3 + cc] = T[rr * 3 + 0] * T[0 * 3 + cc]
                                       + T[rr * 3 + 1] * T[1 * 3 + cc]
                                       + T[rr * 3 + 2] * T[2 * 3 + cc];
#pragma unroll
                for (int i = 0; i < 9; ++i) T[i] = U[i];
            }
#pragma unroll
            for (int j = 0; j < 9; ++j)
                out[(size_t)(9 + j) * KC + ob] = T[j];
        }
    }
}

extern "C" void kernel_launch(void* const* d_in, const int* in_sizes, int n_in,
                              void* d_out, int out_size, void* d_ws, size_t ws_size,
                              hipStream_t stream) {
    const float* x   = (const float*)d_in[0];
    const float* Wo1 = (const float*)d_in[1];
    const float* bo1 = (const float*)d_in[2];
    const float* Wo2 = (const float*)d_in[3];
    const float* bo2 = (const float*)d_in[4];
    const float* Wo3 = (const float*)d_in[5];
    const float* bo3 = (const float*)d_in[6];
    const float* Wt1 = (const float*)d_in[7];
    const float* bt1 = (const float*)d_in[8];
    const float* Wt2 = (const float*)d_in[9];
    const float* bt2 = (const float*)d_in[10];
    const float* Wt3 = (const float*)d_in[11];
    const float* bt3 = (const float*)d_in[12];

    u16* ws = (u16*)d_ws;
    float* out = (float*)d_out;

    hipLaunchKernelGGL(prep, dim3(16), dim3(256), 0, stream,
                       Wo1, bo1, Wo2, bo2, Wo3, bo3,
                       Wt1, bt1, Wt2, bt2, Wt3, bt3, ws);
    hipLaunchKernelGGL(mlp_mfma, dim3(512), dim3(256), 0, stream,
                       x, ws, out);
}